// Round 6
// baseline (523.486 us; speedup 1.0000x reference)
//
#include <hip/hip_runtime.h>
#include <hip/hip_bf16.h>
#include <cstdint>

// Problem constants (B=2,S=4096,D=2048,E=8,SH=2,F=512,K=2)
#define TOKENS   8192
#define D_DIM    2048
#define F_DIM    512
#define NE       8
#define NSH      2
#define NZ       10
#define OUT_ELEMS (TOKENS * D_DIM)

// pair bookkeeping: routed capacity padded to 128-row tiles, then shared pairs
#define RCAP     17408                  // sum ceil(c_e/128)*128 <= 16384+8*127
#define SH_BASE  RCAP
#define NPAIRS   (RCAP + 2 * TOKENS)    // 33792
#define MAX_RT   136                    // max routed 128-row M-tiles
#define G1_SLOTS (MAX_RT + 128)         // 264 (gemm1: +128 shared pair-tiles)
#define G2_SLOTS (MAX_RT + 64)          // 200 (gemm2: +64 shared token-tiles)

typedef __attribute__((ext_vector_type(8))) short bf16x8;
typedef __attribute__((ext_vector_type(4))) float f32x4;

__device__ __forceinline__ short f2bf(float f) {
  union { float f; uint32_t u; } v; v.f = f;
  uint32_t r = (v.u + 0x7fffu + ((v.u >> 16) & 1u)) >> 16;
  return (short)r;
}
__device__ __forceinline__ float bf2f(short s) {
  union { float f; uint32_t u; } v; v.u = ((uint32_t)(uint16_t)s) << 16; return v.f;
}

__device__ __forceinline__ void gload_lds16(const void* g, void* l) {
  __builtin_amdgcn_global_load_lds(
      (const __attribute__((address_space(1))) unsigned int*)g,
      (__attribute__((address_space(3))) unsigned int*)l,
      16, 0, 0);
}

// ------------- transpose-convert fp32 (R,C) -> bf16 (C,R), batched ----------
__global__ void k_transpose(const float* __restrict__ in, short* __restrict__ out,
                            int R, int C) {
  __shared__ float tile[32][33];
  int b = blockIdx.z;
  in  += (size_t)b * R * C;
  out += (size_t)b * R * C;
  int c0 = blockIdx.x * 32, r0 = blockIdx.y * 32;
  #pragma unroll
  for (int i = 0; i < 32; i += 8) {
    int r = r0 + threadIdx.y + i, c = c0 + threadIdx.x;
    tile[threadIdx.y + i][threadIdx.x] = in[(size_t)r * C + c];
  }
  __syncthreads();
  #pragma unroll
  for (int i = 0; i < 32; i += 8) {
    int c = c0 + threadIdx.y + i, r = r0 + threadIdx.x;
    out[(size_t)c * R + r] = f2bf(tile[threadIdx.x][threadIdx.y + i]);
  }
}

// ---------------- zero pad region of pair arrays ----------------------------
__global__ void k_init(int* __restrict__ pair_tok, float* __restrict__ pair_gate) {
  int i = blockIdx.x * blockDim.x + threadIdx.x;
  if (i < RCAP) { pair_tok[i] = 0; pair_gate[i] = 0.f; }
}

// -------- router: wave-per-token, fp32, exact top-2; also writes xb bf16 ----
__global__ __launch_bounds__(256) void k_router(
    const float* __restrict__ x, const float* __restrict__ rw,
    const float* __restrict__ rb, short* __restrict__ xb,
    int2* __restrict__ ti, float2* __restrict__ tg) {
  int wave = threadIdx.x >> 6;
  int lane = threadIdx.x & 63;
  int t = blockIdx.x * 4 + wave;
  const float* xr = x + (size_t)t * D_DIM;
  short* xbr = xb + (size_t)t * D_DIM;
  float acc[NE];
  #pragma unroll
  for (int e = 0; e < NE; e++) acc[e] = 0.f;
  for (int d = lane; d < D_DIM; d += 64) {
    float xv = xr[d];
    xbr[d] = f2bf(xv);
    #pragma unroll
    for (int e = 0; e < NE; e++) acc[e] += xv * rw[e * D_DIM + d];
  }
  #pragma unroll
  for (int e = 0; e < NE; e++) {
    #pragma unroll
    for (int off = 32; off > 0; off >>= 1) acc[e] += __shfl_xor(acc[e], off);
  }
  if (lane == 0) {
    float lg[NE];
    #pragma unroll
    for (int e = 0; e < NE; e++) lg[e] = acc[e] + rb[e];
    int i0 = 0;
    #pragma unroll
    for (int e = 1; e < NE; e++) if (lg[e] > lg[i0]) i0 = e;
    int i1 = (i0 == 0) ? 1 : 0;
    #pragma unroll
    for (int e = 0; e < NE; e++) if (e != i0 && e != i1 && lg[e] > lg[i1]) i1 = e;
    float e1 = __expf(lg[i1] - lg[i0]);
    float inv = 1.f / (1.f + e1);
    ti[t] = make_int2(i0, i1);
    tg[t] = make_float2(inv, e1 * inv);
  }
}

// ------------- count + segment bases + tile table (single block) ------------
// meta: [0..7]=counts [8..15]=cursor [16..17]=loss counts [18]=n_routed_tiles
//       [19..26]=seg_base
__global__ __launch_bounds__(1024) void k_count(
    const int2* __restrict__ ti, int* __restrict__ meta,
    int* __restrict__ tile_z, int* __restrict__ tile_row) {
  __shared__ int cnt[NE + 2];
  if (threadIdx.x < NE + 2) cnt[threadIdx.x] = 0;
  __syncthreads();
  int loc[NE]; int l0 = 0, l1 = 0;
  #pragma unroll
  for (int e = 0; e < NE; e++) loc[e] = 0;
  for (int t = threadIdx.x; t < TOKENS; t += 1024) {
    int2 ii = ti[t];
    loc[ii.x]++; loc[ii.y]++;
    l0 += (ii.x == 0); l1 += (ii.y == 1);
  }
  #pragma unroll
  for (int e = 0; e < NE; e++) if (loc[e]) atomicAdd(&cnt[e], loc[e]);
  if (l0) atomicAdd(&cnt[NE], l0);
  if (l1) atomicAdd(&cnt[NE + 1], l1);
  __syncthreads();
  if (threadIdx.x == 0) {
    int base = 0, nrt = 0;
    #pragma unroll
    for (int e = 0; e < NE; e++) {
      int c = cnt[e];
      meta[e] = c;
      meta[19 + e] = base;
      meta[8 + e] = 0;                       // cursor
      int nt = (c + 127) >> 7;
      for (int i = 0; i < nt; i++) { tile_z[nrt] = e; tile_row[nrt] = base + i * 128; nrt++; }
      base += nt * 128;
    }
    meta[16] = cnt[NE]; meta[17] = cnt[NE + 1];
    meta[18] = nrt;
    for (int i = 0; i < 128; i++) {          // shared pair-tiles (gemm1)
      tile_z[MAX_RT + i] = NE + (i >> 6);
      tile_row[MAX_RT + i] = SH_BASE + (i >> 6) * TOKENS + (i & 63) * 128;
    }
  }
}

// ---------------- assignment: ballot-scan within wave + inverse map ---------
__global__ __launch_bounds__(256) void k_assign(
    const int2* __restrict__ ti, const float2* __restrict__ tg,
    int* __restrict__ meta, int* __restrict__ pair_tok, float* __restrict__ pair_gate,
    int2* __restrict__ pos) {
  int t = blockIdx.x * 256 + threadIdx.x;
  int lane = threadIdx.x & 63;
  int2 ii = ti[t];
  float2 gg = tg[t];
  int2 mypos;
  unsigned long long below = (1ull << lane) - 1ull;
  #pragma unroll
  for (int e = 0; e < NE; e++) {
    unsigned long long m0 = __ballot(ii.x == e);
    unsigned long long m1 = __ballot(ii.y == e);
    unsigned c = __popcll(m0) + __popcll(m1);
    unsigned base = 0;
    if (lane == 0 && c) base = atomicAdd((unsigned*)&meta[8 + e], c);
    base = __shfl((int)base, 0);
    int seg = meta[19 + e];
    if (ii.x == e) {
      int p = seg + base + __popcll(m0 & below);
      pair_tok[p] = t; pair_gate[p] = gg.x; mypos.x = p;
    }
    if (ii.y == e) {
      int p = seg + base + __popcll(m0) + __popcll(m1 & below);
      pair_tok[p] = t; pair_gate[p] = gg.y; mypos.y = p;
    }
  }
  pos[t] = mypos;
  pair_tok[SH_BASE + t] = t;            pair_gate[SH_BASE + t] = 1.f;
  pair_tok[SH_BASE + TOKENS + t] = t;   pair_gate[SH_BASE + TOKENS + t] = 1.f;
}

// ---------------- aux loss --------------------------------------------------
__global__ void k_loss(const int* __restrict__ meta, float* __restrict__ out_loss) {
  if (threadIdx.x == 0 && blockIdx.x == 0) {
    float p0 = (float)meta[16] / 16384.0f + 1e-8f;
    float p1 = (float)meta[17] / 16384.0f + 1e-8f;
    float rest = 6.0f * (1e-8f * logf(1e-8f));
    out_loss[0] = -(p0 * logf(p0) + p1 * logf(p1) + rest);
  }
}

// ============================================================================
// 128x128-tile, 4-wave, 4-phase/K-tile (BK=64) GEMM core, dbuf LDS = 64 KB
// -> 2 blocks/CU co-resident. LDS half h at [h*4096, +4096) shorts:
//   chunk(row,c8) at (row>>4)*1024 + c8*128 + (row&15)*8 ; wave wv stages
//   shorts [wv*1024, +1024) of the half (linear dest, 2 gloads).
// Phase sequence per K-tile (operand-reuse order; stage order A0,B0,B1,A1):
//   P1(0,0): vm4|bar|read A0,B0|stage A0'|lgkm|8 MFMA
//   P2(0,1): vm4|bar|read B1   |stage B0'|lgkm|8 MFMA   (A0 kept in regs)
//   P3(1,1): vm4|bar|read A1   |stage B1'|lgkm|8 MFMA   (B1 kept)
//   P4(1,0):     bar|read B0   |stage A1'|lgkm|8 MFMA   (A1 kept)
// vmcnt FIFO ledger (2 loads/stage, invariant 8 outstanding at P1 top):
//   P1 vm4 drains A0,B0; P2 drains B1; P3 drains A1; P4 none. All reads of
//   buf[cur] are preceded by a barrier after every wave's drain; stores to
//   buf[nb] are >=2 barriers after the last read of that region. Never vm0
//   inside the loop.
// ============================================================================
#define PHASE(DO_WAIT, RD_A, AH, RD_B, BH, MH, NH, STAGE_STMT) do {           \
    if (DO_WAIT) asm volatile("s_waitcnt vmcnt(4)" ::: "memory");             \
    __builtin_amdgcn_s_barrier();                                             \
    asm volatile("" ::: "memory");                                            \
    if (RD_A) {                                                               \
      _Pragma("unroll") for (int m_ = 0; m_ < 2; m_++)                        \
        _Pragma("unroll") for (int kk = 0; kk < 2; kk++)                      \
          afr[m_][kk] = *(const bf16x8*)&As[cur][(AH)*4096 + (wm*2+m_)*1024 + kk*512 + ldo]; \
    }                                                                         \
    if (RD_B) {                                                               \
      _Pragma("unroll") for (int n_ = 0; n_ < 2; n_++)                        \
        _Pragma("unroll") for (int kk = 0; kk < 2; kk++)                      \
          bfr[n_][kk] = *(const bf16x8*)&Bs[cur][(BH)*4096 + (wn*2+n_)*1024 + kk*512 + ldo]; \
    }                                                                         \
    STAGE_STMT;                                                               \
    asm volatile("s_waitcnt lgkmcnt(0)" ::: "memory");                        \
    __builtin_amdgcn_sched_barrier(0);                                        \
    __builtin_amdgcn_s_setprio(1);                                            \
    _Pragma("unroll") for (int m_ = 0; m_ < 2; m_++)                          \
      _Pragma("unroll") for (int n_ = 0; n_ < 2; n_++)                        \
        _Pragma("unroll") for (int kk = 0; kk < 2; kk++)                      \
          acc[(MH)*2+m_][(NH)*2+n_] = __builtin_amdgcn_mfma_f32_16x16x32_bf16( \
              afr[m_][kk], bfr[n_][kk], acc[(MH)*2+m_][(NH)*2+n_], 0, 0, 0);  \
    __builtin_amdgcn_s_setprio(0);                                            \
  } while (0)

// ---------------- GEMM1: H[p] = gelu(x[tok(p)]@W1[z]+b1)*gate ---------------
// grid (4, 264): x=bn (128-col tile of F=512), y=slot. block 256 (4 waves).
__global__ __launch_bounds__(256, 2) void k_gemm1(
    const short* __restrict__ xb, const short* __restrict__ w1t,
    const float* __restrict__ eb1, const float* __restrict__ sb1,
    const int* __restrict__ meta, const int* __restrict__ tile_z,
    const int* __restrict__ tile_row, const int* __restrict__ pair_tok,
    const float* __restrict__ pair_gate, short* __restrict__ H) {
  const int slot = blockIdx.y;
  if (slot < MAX_RT && slot >= meta[18]) return;
  const int z = tile_z[slot];
  const int row0 = tile_row[slot];
  const int bn = blockIdx.x;
  __shared__ __align__(16) short As[2][8192];
  __shared__ __align__(16) short Bs[2][8192];
  const int tid = threadIdx.x;
  const int lane = tid & 63;
  const int wv = tid >> 6;          // 0..3
  const int wm = wv >> 1;           // 0..1
  const int wn = wv & 1;            // 0..1
  const int ldo = (lane >> 4) * 128 + (lane & 15) * 8;

  // staging geometry: row-within-half = wv*16 + (lane&15); cols via lane>>4
  const int srlow = (wv << 4) | (lane & 15);
  const int scol0 = (lane >> 4) * 8;
  const short* aptr[2]; const short* bptr[2];
  {
    aptr[0] = xb + (size_t)pair_tok[row0 + srlow] * D_DIM + scol0;
    aptr[1] = xb + (size_t)pair_tok[row0 + 64 + srlow] * D_DIM + scol0;
    const short* wb = w1t + (size_t)z * F_DIM * D_DIM;
    bptr[0] = wb + (size_t)(bn * 128 + srlow) * D_DIM + scol0;
    bptr[1] = wb + (size_t)(bn * 128 + 64 + srlow) * D_DIM + scol0;
  }

  f32x4 acc[4][4];
  #pragma unroll
  for (int m = 0; m < 4; m++)
    #pragma unroll
    for (int n = 0; n < 4; n++) acc[m][n] = (f32x4)(0.f);

  #define ST_A(B, HH, K0) do {                                        \
      gload_lds16(aptr[HH] + (K0),      &As[B][(HH)*4096 + wv*1024]);  \
      gload_lds16(aptr[HH] + (K0) + 32, &As[B][(HH)*4096 + wv*1024 + 512]); } while (0)
  #define ST_B(B, HH, K0) do {                                        \
      gload_lds16(bptr[HH] + (K0),      &Bs[B][(HH)*4096 + wv*1024]);  \
      gload_lds16(bptr[HH] + (K0) + 32, &Bs[B][(HH)*4096 + wv*1024 + 512]); } while (0)

  // prologue: tile 0 -> buf 0, order A0,B0,B1,A1 (8 loads outstanding)
  ST_A(0, 0, 0); ST_B(0, 0, 0); ST_B(0, 1, 0); ST_A(0, 1, 0);

  const int NT = D_DIM / 64;   // 32
  for (int t = 0; t < NT; ++t) {
    const int cur = t & 1, nb = cur ^ 1;
    const int kn = ((t + 1 < NT) ? (t + 1) : t) * 64;
    bf16x8 afr[2][2], bfr[2][2];
    PHASE(1, 1, 0, 1, 0, 0, 0, ST_A(nb, 0, kn));
    PHASE(1, 0, 0, 1, 1, 0, 1, ST_B(nb, 0, kn));
    PHASE(1, 1, 1, 0, 0, 1, 1, ST_B(nb, 1, kn));
    PHASE(0, 0, 0, 1, 0, 1, 0, ST_A(nb, 1, kn));
  }
  #undef ST_A
  #undef ST_B
  asm volatile("s_waitcnt vmcnt(0)" ::: "memory");

  const float* b1 = (z < NE) ? (eb1 + z * F_DIM) : (sb1 + (size_t)(z - NE) * F_DIM);
  #pragma unroll
  for (int mh = 0; mh < 2; mh++) {
    #pragma unroll
    for (int m_ = 0; m_ < 2; m_++) {
      #pragma unroll
      for (int r = 0; r < 4; r++) {
        int row = mh * 64 + wm * 32 + m_ * 16 + (lane >> 4) * 4 + r;
        float g = pair_gate[row0 + row];
        #pragma unroll
        for (int nh = 0; nh < 2; nh++) {
          #pragma unroll
          for (int n_ = 0; n_ < 2; n_++) {
            int col = bn * 128 + nh * 64 + wn * 32 + n_ * 16 + (lane & 15);
            float c = acc[mh * 2 + m_][nh * 2 + n_][r] + b1[col];
            float h = 0.5f * c * (1.0f + erff(c * 0.70710678118654752440f));
            H[(size_t)(row0 + row) * F_DIM + col] = f2bf(h * g);
          }
        }
      }
    }
  }
}

// ---------------- GEMM2 unified: routed->Yr (K=512), shared->out (K=1024) ---
// grid (16, 200): x=bn (128-col tile of D=2048), y=slot. block 256.
__global__ __launch_bounds__(256, 2) void k_gemm2(
    const short* __restrict__ Hb, const short* __restrict__ w2t,
    const int* __restrict__ meta, const int* __restrict__ tile_z,
    const int* __restrict__ tile_row,
    const int2* __restrict__ ti, const float2* __restrict__ tg,
    const float* __restrict__ eb2, const float* __restrict__ sb2,
    short* __restrict__ Yr, float* __restrict__ out) {
  const int slot = blockIdx.y;
  const bool shmode = (slot >= MAX_RT);
  if (!shmode && slot >= meta[18]) return;
  const int z = shmode ? 0 : tile_z[slot];
  const int row0 = shmode ? 0 : tile_row[slot];
  const int t0 = shmode ? (slot - MAX_RT) * 128 : 0;
  const int bn = blockIdx.x;
  __shared__ __align__(16) short As[2][8192];
  __shared__ __align__(16) short Bs[2][8192];
  const int tid = threadIdx.x;
  const int lane = tid & 63;
  const int wv = tid >> 6;
  const int wm = wv >> 1;
  const int wn = wv & 1;
  const int ldo = (lane >> 4) * 128 + (lane & 15) * 8;

  const int srlow = (wv << 4) | (lane & 15);
  const int scol0 = (lane >> 4) * 8;

  f32x4 acc[4][4];
  #pragma unroll
  for (int m = 0; m < 4; m++)
    #pragma unroll
    for (int n = 0; n < 4; n++) acc[m][n] = (f32x4)(0.f);

  auto stA = [&](int b, int h, int k0) {
    const short* p;
    if (shmode) {
      p = Hb + (size_t)(SH_BASE + ((k0 >= F_DIM) ? TOKENS : 0) + t0 + h * 64 + srlow) * F_DIM
            + (k0 & (F_DIM - 1)) + scol0;
    } else {
      p = Hb + (size_t)(row0 + h * 64 + srlow) * F_DIM + k0 + scol0;
    }
    gload_lds16(p,      &As[b][h * 4096 + wv * 1024]);
    gload_lds16(p + 32, &As[b][h * 4096 + wv * 1024 + 512]);
  };
  auto stB = [&](int b, int h, int k0) {
    const short* p;
    if (shmode) {
      p = w2t + (size_t)(NE + ((k0 >= F_DIM) ? 1 : 0)) * D_DIM * F_DIM
              + (size_t)(bn * 128 + h * 64 + srlow) * F_DIM + (k0 & (F_DIM - 1)) + scol0;
    } else {
      p = w2t + (size_t)z * D_DIM * F_DIM
              + (size_t)(bn * 128 + h * 64 + srlow) * F_DIM + k0 + scol0;
    }
    gload_lds16(p,      &Bs[b][h * 4096 + wv * 1024]);
    gload_lds16(p + 32, &Bs[b][h * 4096 + wv * 1024 + 512]);
  };

  // prologue
  stA(0, 0, 0); stB(0, 0, 0); stB(0, 1, 0); stA(0, 1, 0);

  const int NT = shmode ? (2 * F_DIM / 64) : (F_DIM / 64);   // 16 or 8
  for (int t = 0; t < NT; ++t) {
    const int cur = t & 1, nb = cur ^ 1;
    const int kn = ((t + 1 < NT) ? (t + 1) : t) * 64;
    bf16x8 afr[2][2], bfr[2][2];
    PHASE(1, 1, 0, 1, 0, 0, 0, stA(nb, 0, kn));
    PHASE(1, 0, 0, 1, 1, 0, 1, stB(nb, 0, kn));
    PHASE(1, 1, 1, 0, 0, 1, 1, stB(nb, 1, kn));
    PHASE(0, 0, 0, 1, 0, 1, 0, stA(nb, 1, kn));
  }
  asm volatile("s_waitcnt vmcnt(0)" ::: "memory");

  if (!shmode) {
    #pragma unroll
    for (int mh = 0; mh < 2; mh++) {
      #pragma unroll
      for (int m_ = 0; m_ < 2; m_++) {
        #pragma unroll
        for (int r = 0; r < 4; r++) {
          int row = mh * 64 + wm * 32 + m_ * 16 + (lane >> 4) * 4 + r;
          #pragma unroll
          for (int nh = 0; nh < 2; nh++) {
            #pragma unroll
            for (int n_ = 0; n_ < 2; n_++) {
              int col = bn * 128 + nh * 64 + wn * 32 + n_ * 16 + (lane & 15);
              Yr[(size_t)(row0 + row) * D_DIM + col] = f2bf(acc[mh * 2 + m_][nh * 2 + n_][r]);
            }
          }
        }
      }
    }
  } else {
    #pragma unroll
    for (int mh = 0; mh < 2; mh++) {
      #pragma unroll
      for (int m_ = 0; m_ < 2; m_++) {
        #pragma unroll
        for (int r = 0; r < 4; r++) {
          int row = t0 + mh * 64 + wm * 32 + m_ * 16 + (lane >> 4) * 4 + r;
          int2 ii = ti[row]; float2 gg = tg[row];
          #pragma unroll
          for (int nh = 0; nh < 2; nh++) {
            #pragma unroll
            for (int n_ = 0; n_ < 2; n_++) {
              int col = bn * 128 + nh * 64 + wn * 32 + n_ * 16 + (lane & 15);
              float v = acc[mh * 2 + m_][nh * 2 + n_][r]
                      + gg.x * eb2[(size_t)ii.x * D_DIM + col]
                      + gg.y * eb2[(size_t)ii.y * D_DIM + col]
                      + sb2[col] + sb2[D_DIM + col];
              out[(size_t)row * D_DIM + col] = v;
            }
          }
        }
      }
    }
  }
}

// ---------------- combine: out[t] += Yr[pos0] + Yr[pos1] --------------------
__global__ __launch_bounds__(256) void k_combine(
    const short* __restrict__ Yr, const int2* __restrict__ pos,
    float* __restrict__ out) {
  int idx = blockIdx.x * 256 + threadIdx.x;   // over TOKENS*D_DIM/8
  int t = idx >> 8;
  int c = (idx & 255) * 8;
  int2 p = pos[t];
  bf16x8 a = *(const bf16x8*)&Yr[(size_t)p.x * D_DIM + c];
  bf16x8 b = *(const bf16x8*)&Yr[(size_t)p.y * D_DIM + c];
  float4 o0 = *(float4*)&out[(size_t)t * D_DIM + c];
  float4 o1 = *(float4*)&out[(size_t)t * D_DIM + c + 4];
  o0.x += bf2f(a[0]) + bf2f(b[0]);
  o0.y += bf2f(a[1]) + bf2f(b[1]);
  o0.z += bf2f(a[2]) + bf2f(b[2]);
  o0.w += bf2f(a[3]) + bf2f(b[3]);
  o1.x += bf2f(a[4]) + bf2f(b[4]);
  o1.y += bf2f(a[5]) + bf2f(b[5]);
  o1.z += bf2f(a[6]) + bf2f(b[6]);
  o1.w += bf2f(a[7]) + bf2f(b[7]);
  *(float4*)&out[(size_t)t * D_DIM + c] = o0;
  *(float4*)&out[(size_t)t * D_DIM + c + 4] = o1;
}

// ---------------------------------------------------------------------------
extern "C" void kernel_launch(void* const* d_in, const int* in_sizes, int n_in,
                              void* d_out, int out_size, void* d_ws, size_t ws_size,
                              hipStream_t stream) {
  (void)in_sizes; (void)n_in; (void)out_size; (void)ws_size;
  const float* x        = (const float*)d_in[0];
  const float* router_w = (const float*)d_in[1];
  const float* router_b = (const float*)d_in[2];
  const float* ew1      = (const float*)d_in[3];
  const float* eb1      = (const float*)d_in[4];
  const float* ew2      = (const float*)d_in[5];
  const float* eb2      = (const float*)d_in[6];
  const float* sw1      = (const float*)d_in[7];
  const float* sb1      = (const float*)d_in[8];
  const float* sw2      = (const float*)d_in[9];
  const float* sb2      = (const float*)d_in[10];
  float* out = (float*)d_out;

  // workspace layout (Yr aliases xb+w1t+overhang; dead after k_gemm1):
  //   w2t 20.97MB | Hbuf 34.6MB | small ~0.6MB | xb 33.55MB | w1t 20.97MB |
  //   Yr-overhang ~17MB  => total ~128MB
  char* ws = (char*)d_ws;
  short*  w2t       = (short*)ws;
  short*  Hbuf      = w2t + (size_t)NZ * D_DIM * F_DIM;
  int2*   ti        = (int2*)(Hbuf + (size_t)NPAIRS * F_DIM);
  float2* tg        = (float2*)(ti + TOKENS);
  int2*   pos       = (int2*)(tg + TOKENS);
  int*    pair_tok  = (int*)(pos + TOKENS);
  float*  pair_gate = (float*)(pair_tok + NPAIRS);
  int*    meta      = (int*)(pair_gate + NPAIRS);
  int*    tile_z    = meta + 32;
  int*    tile_row  = tile_z + 512;
  short*  xb        = (short*)(((uintptr_t)(tile_row + 512) + 255) & ~(uintptr_t)255);
  short*  w1t       = xb + (size_t)TOKENS * D_DIM;
  short*  Yr        = xb;   // alias (valid after k_gemm1 completes)

  k_transpose<<<dim3(F_DIM / 32, D_DIM / 32, NE),  dim3(32, 8), 0, stream>>>(ew1, w1t, D_DIM, F_DIM);
  k_transpose<<<dim3(F_DIM / 32, D_DIM / 32, NSH), dim3(32, 8), 0, stream>>>(sw1, w1t + (size_t)NE * F_DIM * D_DIM, D_DIM, F_DIM);
  k_transpose<<<dim3(D_DIM / 32, F_DIM / 32, NE),  dim3(32, 8), 0, stream>>>(ew2, w2t, F_DIM, D_DIM);
  k_transpose<<<dim3(D_DIM / 32, F_DIM / 32, NSH), dim3(32, 8), 0, stream>>>(sw2, w2t + (size_t)NE * D_DIM * F_DIM, F_DIM, D_DIM);

  k_init<<<(RCAP + 255) / 256, 256, 0, stream>>>(pair_tok, pair_gate);
  k_router<<<TOKENS / 4, 256, 0, stream>>>(x, router_w, router_b, xb, ti, tg);
  k_count<<<1, 1024, 0, stream>>>(ti, meta, tile_z, tile_row);
  k_assign<<<TOKENS / 256, 256, 0, stream>>>(ti, tg, meta, pair_tok, pair_gate, pos);
  k_loss<<<1, 64, 0, stream>>>(meta, out + OUT_ELEMS);

  k_gemm1<<<dim3(4, G1_SLOTS), 256, 0, stream>>>(
      xb, w1t, eb1, sb1, meta, tile_z, tile_row, pair_tok, pair_gate, Hbuf);
  k_gemm2<<<dim3(16, G2_SLOTS), 256, 0, stream>>>(
      Hbuf, w2t, meta, tile_z, tile_row, ti, tg, eb2, sb2, Yr, out);
  k_combine<<<OUT_ELEMS / 8 / 256, 256, 0, stream>>>(Yr, pos, out);
}

// Round 7
// 479.600 us; speedup vs baseline: 1.0915x; 1.0915x over previous
//
#include <hip/hip_runtime.h>
#include <hip/hip_bf16.h>
#include <cstdint>

// Problem constants (B=2,S=4096,D=2048,E=8,SH=2,F=512,K=2)
#define TOKENS   8192
#define D_DIM    2048
#define F_DIM    512
#define NE       8
#define NSH      2
#define NZ       10
#define OUT_ELEMS (TOKENS * D_DIM)

// pair bookkeeping: routed capacity padded to 256-row tiles, then shared pairs
#define RCAP256   18432                 // sum ceil(c_e/256)*256 <= 16384+8*255
#define SH_B256   RCAP256
#define NPAIRS256 (RCAP256 + 2 * TOKENS)  // 34816
#define MAX_RT256 72                    // max routed 256-row M-tiles
#define G1_SLOTS  136                   // 72 routed + 64 shared pair-tiles
#define G2_SLOTS  104                   // 72 routed + 32 shared token-tiles

typedef __attribute__((ext_vector_type(8))) short bf16x8;
typedef __attribute__((ext_vector_type(4))) float f32x4;

__device__ __forceinline__ short f2bf(float f) {
  union { float f; uint32_t u; } v; v.f = f;
  uint32_t r = (v.u + 0x7fffu + ((v.u >> 16) & 1u)) >> 16;
  return (short)r;
}
__device__ __forceinline__ float bf2f(short s) {
  union { float f; uint32_t u; } v; v.u = ((uint32_t)(uint16_t)s) << 16; return v.f;
}

__device__ __forceinline__ void gload_lds16(const void* g, void* l) {
  __builtin_amdgcn_global_load_lds(
      (const __attribute__((address_space(1))) unsigned int*)g,
      (__attribute__((address_space(3))) unsigned int*)l,
      16, 0, 0);
}

// ------------- transpose-convert fp32 (R,C) -> bf16 (C,R), batched ----------
__global__ void k_transpose(const float* __restrict__ in, short* __restrict__ out,
                            int R, int C) {
  __shared__ float tile[32][33];
  int b = blockIdx.z;
  in  += (size_t)b * R * C;
  out += (size_t)b * R * C;
  int c0 = blockIdx.x * 32, r0 = blockIdx.y * 32;
  #pragma unroll
  for (int i = 0; i < 32; i += 8) {
    int r = r0 + threadIdx.y + i, c = c0 + threadIdx.x;
    tile[threadIdx.y + i][threadIdx.x] = in[(size_t)r * C + c];
  }
  __syncthreads();
  #pragma unroll
  for (int i = 0; i < 32; i += 8) {
    int c = c0 + threadIdx.y + i, r = r0 + threadIdx.x;
    out[(size_t)c * R + r] = f2bf(tile[threadIdx.x][threadIdx.y + i]);
  }
}

// ---------------- zero pad region of pair arrays ----------------------------
__global__ void k_init(int* __restrict__ pair_tok, float* __restrict__ pair_gate) {
  int i = blockIdx.x * blockDim.x + threadIdx.x;
  if (i < RCAP256) { pair_tok[i] = 0; pair_gate[i] = 0.f; }
}

// -------- router: wave-per-token, fp32, exact top-2; also writes xb bf16 ----
__global__ __launch_bounds__(256) void k_router(
    const float* __restrict__ x, const float* __restrict__ rw,
    const float* __restrict__ rb, short* __restrict__ xb,
    int2* __restrict__ ti, float2* __restrict__ tg) {
  int wave = threadIdx.x >> 6;
  int lane = threadIdx.x & 63;
  int t = blockIdx.x * 4 + wave;
  const float* xr = x + (size_t)t * D_DIM;
  short* xbr = xb + (size_t)t * D_DIM;
  float acc[NE];
  #pragma unroll
  for (int e = 0; e < NE; e++) acc[e] = 0.f;
  for (int d = lane; d < D_DIM; d += 64) {
    float xv = xr[d];
    xbr[d] = f2bf(xv);
    #pragma unroll
    for (int e = 0; e < NE; e++) acc[e] += xv * rw[e * D_DIM + d];
  }
  #pragma unroll
  for (int e = 0; e < NE; e++) {
    #pragma unroll
    for (int off = 32; off > 0; off >>= 1) acc[e] += __shfl_xor(acc[e], off);
  }
  if (lane == 0) {
    float lg[NE];
    #pragma unroll
    for (int e = 0; e < NE; e++) lg[e] = acc[e] + rb[e];
    int i0 = 0;
    #pragma unroll
    for (int e = 1; e < NE; e++) if (lg[e] > lg[i0]) i0 = e;
    int i1 = (i0 == 0) ? 1 : 0;
    #pragma unroll
    for (int e = 0; e < NE; e++) if (e != i0 && e != i1 && lg[e] > lg[i1]) i1 = e;
    float e1 = __expf(lg[i1] - lg[i0]);
    float inv = 1.f / (1.f + e1);
    ti[t] = make_int2(i0, i1);
    tg[t] = make_float2(inv, e1 * inv);
  }
}

// ------------- count + segment bases + tile table (single block) ------------
// meta: [0..7]=counts [8..15]=cursor [16..17]=loss counts [18]=n_routed_tiles
//       [19..26]=seg_base
__global__ __launch_bounds__(1024) void k_count(
    const int2* __restrict__ ti, int* __restrict__ meta,
    int* __restrict__ tile_z, int* __restrict__ tile_row) {
  __shared__ int cnt[NE + 2];
  if (threadIdx.x < NE + 2) cnt[threadIdx.x] = 0;
  __syncthreads();
  int loc[NE]; int l0 = 0, l1 = 0;
  #pragma unroll
  for (int e = 0; e < NE; e++) loc[e] = 0;
  for (int t = threadIdx.x; t < TOKENS; t += 1024) {
    int2 ii = ti[t];
    loc[ii.x]++; loc[ii.y]++;
    l0 += (ii.x == 0); l1 += (ii.y == 1);
  }
  #pragma unroll
  for (int e = 0; e < NE; e++) if (loc[e]) atomicAdd(&cnt[e], loc[e]);
  if (l0) atomicAdd(&cnt[NE], l0);
  if (l1) atomicAdd(&cnt[NE + 1], l1);
  __syncthreads();
  if (threadIdx.x == 0) {
    int base = 0, nrt = 0;
    #pragma unroll
    for (int e = 0; e < NE; e++) {
      int c = cnt[e];
      meta[e] = c;
      meta[19 + e] = base;
      meta[8 + e] = 0;                       // cursor
      int nt = (c + 255) >> 8;
      for (int i = 0; i < nt; i++) { tile_z[nrt] = e; tile_row[nrt] = base + i * 256; nrt++; }
      base += nt * 256;
    }
    meta[16] = cnt[NE]; meta[17] = cnt[NE + 1];
    meta[18] = nrt;
    for (int i = 0; i < 64; i++) {           // shared pair-tiles (gemm1)
      tile_z[MAX_RT256 + i] = NE + (i >> 5);
      tile_row[MAX_RT256 + i] = SH_B256 + i * 256;
    }
  }
}

// ---------------- assignment: ballot-scan within wave + inverse map ---------
__global__ __launch_bounds__(256) void k_assign(
    const int2* __restrict__ ti, const float2* __restrict__ tg,
    int* __restrict__ meta, int* __restrict__ pair_tok, float* __restrict__ pair_gate,
    int2* __restrict__ pos) {
  int t = blockIdx.x * 256 + threadIdx.x;
  int lane = threadIdx.x & 63;
  int2 ii = ti[t];
  float2 gg = tg[t];
  int2 mypos;
  unsigned long long below = (1ull << lane) - 1ull;
  #pragma unroll
  for (int e = 0; e < NE; e++) {
    unsigned long long m0 = __ballot(ii.x == e);
    unsigned long long m1 = __ballot(ii.y == e);
    unsigned c = __popcll(m0) + __popcll(m1);
    unsigned base = 0;
    if (lane == 0 && c) base = atomicAdd((unsigned*)&meta[8 + e], c);
    base = __shfl((int)base, 0);
    int seg = meta[19 + e];
    if (ii.x == e) {
      int p = seg + base + __popcll(m0 & below);
      pair_tok[p] = t; pair_gate[p] = gg.x; mypos.x = p;
    }
    if (ii.y == e) {
      int p = seg + base + __popcll(m0) + __popcll(m1 & below);
      pair_tok[p] = t; pair_gate[p] = gg.y; mypos.y = p;
    }
  }
  pos[t] = mypos;
  pair_tok[SH_B256 + t] = t;            pair_gate[SH_B256 + t] = 1.f;
  pair_tok[SH_B256 + TOKENS + t] = t;   pair_gate[SH_B256 + TOKENS + t] = 1.f;
}

// ---------------- aux loss --------------------------------------------------
__global__ void k_loss(const int* __restrict__ meta, float* __restrict__ out_loss) {
  if (threadIdx.x == 0 && blockIdx.x == 0) {
    float p0 = (float)meta[16] / 16384.0f + 1e-8f;
    float p1 = (float)meta[17] / 16384.0f + 1e-8f;
    float rest = 6.0f * (1e-8f * logf(1e-8f));
    out_loss[0] = -(p0 * logf(p0) + p1 * logf(p1) + rest);
  }
}

// ============================================================================
// 256x256-tile, 8-wave, BK=32, TRIPLE-buffered (96 KB) deep-pipeline core.
// LDS per buffer per matrix: 16 rgs x 512 shorts; chunk(row,c8) at
//   (row>>4)*512 + c8*128 + (row&15)*8, c8 = k-chunk (l>>4). Staged linearly:
//   wave wv writes 1KB at rg=(h*8+wv) from per-lane global src (proven layout).
// Schedule: tile t reads buf[t%3]; its 4 phases stage tile t+2's 4 chunks
//   into buf[(t+2)%3] (freed at end of tile t-1). Slack = 4-7 phases.
// Ledger (per wave, 4 loads/tile): top of tile t in-flight = {t:4, t+1:4};
//   vmcnt(4) drains tile t's, leaves t+1's. One barrier per K-tile publishes
//   all waves' tile-t chunks. Phases within a tile need no barriers: reads
//   are from the published buffer; stage-writes target a region whose last
//   reads (tile t-1) completed before this tile's barrier. Last tile: vmcnt(0).
// Per wave: C = 128x64 (acc[8][4]), 14 ds_read_b128 + 32 MFMA per K-tile.
// ============================================================================
#define PH_CORE(MH, NQ, RD_A, RD_B, STAGE_STMT) do {                          \
    if (RD_A) { _Pragma("unroll") for (int f = 0; f < 4; f++)                 \
      afr[f] = *(const bf16x8*)&Acur[(wm * 8 + (MH) * 4 + f) * 512 + ldo]; }  \
    if (RD_B) { _Pragma("unroll") for (int g = 0; g < 2; g++)                 \
      bfr[g] = *(const bf16x8*)&Bcur[(wn * 4 + (NQ) * 2 + g) * 512 + ldo]; }  \
    STAGE_STMT;                                                               \
    asm volatile("s_waitcnt lgkmcnt(0)" ::: "memory");                        \
    __builtin_amdgcn_sched_barrier(0);                                        \
    __builtin_amdgcn_s_setprio(1);                                            \
    _Pragma("unroll") for (int f = 0; f < 4; f++)                             \
      _Pragma("unroll") for (int g = 0; g < 2; g++)                           \
        acc[(MH) * 4 + f][(NQ) * 2 + g] =                                     \
            __builtin_amdgcn_mfma_f32_16x16x32_bf16(                          \
                afr[f], bfr[g], acc[(MH) * 4 + f][(NQ) * 2 + g], 0, 0, 0);    \
    __builtin_amdgcn_s_setprio(0);                                            \
  } while (0)

#define KTILE_TOP(NTV)                                                        \
    if (t + 1 < (NTV)) asm volatile("s_waitcnt vmcnt(4)" ::: "memory");       \
    else               asm volatile("s_waitcnt vmcnt(0)" ::: "memory");       \
    __builtin_amdgcn_s_barrier();                                             \
    asm volatile("" ::: "memory");

// ---------------- GEMM1: H[p] = gelu(x[tok(p)]@W1[z]+b1)*gate ---------------
// grid (2, 136): x=bn (256-col tile of F=512), y=slot. block 512.
__global__ __launch_bounds__(512, 2) void k_gemm1(
    const short* __restrict__ xb, const short* __restrict__ w1t,
    const float* __restrict__ eb1, const float* __restrict__ sb1,
    const int* __restrict__ meta, const int* __restrict__ tile_z,
    const int* __restrict__ tile_row, const int* __restrict__ pair_tok,
    const float* __restrict__ pair_gate, short* __restrict__ H) {
  const int slot = blockIdx.y;
  if (slot < MAX_RT256 && slot >= meta[18]) return;
  const int z = tile_z[slot];
  const int row0 = tile_row[slot];
  const int bn = blockIdx.x;
  __shared__ __align__(16) short As[3][8192];
  __shared__ __align__(16) short Bs[3][8192];
  const int tid = threadIdx.x;
  const int lane = tid & 63;
  const int wv = tid >> 6;          // 0..7
  const int wm = wv >> 2;           // 0..1 : rows wm*128..+128
  const int wn = wv & 3;            // 0..3 : cols wn*64..+64
  const int ldo = (lane >> 4) * 128 + (lane & 15) * 8;

  const int srlow = (wv << 4) | (lane & 15);
  const int scol0 = (lane >> 4) * 8;
  const short* aptr[2]; const short* bptr[2];
  {
    aptr[0] = xb + (size_t)pair_tok[row0 + srlow] * D_DIM + scol0;
    aptr[1] = xb + (size_t)pair_tok[row0 + 128 + srlow] * D_DIM + scol0;
    const short* wb = w1t + (size_t)z * F_DIM * D_DIM;
    bptr[0] = wb + (size_t)(bn * 256 + srlow) * D_DIM + scol0;
    bptr[1] = wb + (size_t)(bn * 256 + 128 + srlow) * D_DIM + scol0;
  }

  f32x4 acc[8][4];
  #pragma unroll
  for (int m = 0; m < 8; m++)
    #pragma unroll
    for (int n = 0; n < 4; n++) acc[m][n] = (f32x4)(0.f);

  #define STG_A(BUF, HH, TT) gload_lds16(aptr[HH] + (TT) * 32, &As[BUF][((HH) * 8 + wv) * 512])
  #define STG_B(BUF, HH, TT) gload_lds16(bptr[HH] + (TT) * 32, &Bs[BUF][((HH) * 8 + wv) * 512])

  // prologue: tiles 0 -> buf0, 1 -> buf1 (8 loads in flight)
  STG_A(0, 0, 0); STG_A(0, 1, 0); STG_B(0, 0, 0); STG_B(0, 1, 0);
  STG_A(1, 0, 1); STG_A(1, 1, 1); STG_B(1, 0, 1); STG_B(1, 1, 1);

  const int NT = D_DIM / 32;   // 64
  int rd = 0;
  for (int t = 0; t < NT; ++t) {
    const short* Acur = &As[rd][0];
    const short* Bcur = &Bs[rd][0];
    const int st = (rd + 2 >= 3) ? rd - 1 : rd + 2;
    const int tt = t + 2;
    KTILE_TOP(NT);
    bf16x8 afr[4], bfr[2];
    PH_CORE(0, 0, 1, 1, if (tt < NT) STG_A(st, 0, tt));
    PH_CORE(0, 1, 0, 1, if (tt < NT) STG_A(st, 1, tt));
    PH_CORE(1, 1, 1, 0, if (tt < NT) STG_B(st, 0, tt));
    PH_CORE(1, 0, 0, 1, if (tt < NT) STG_B(st, 1, tt));
    rd = (rd + 1 == 3) ? 0 : rd + 1;
  }
  #undef STG_A
  #undef STG_B

  const float* b1 = (z < NE) ? (eb1 + z * F_DIM) : (sb1 + (size_t)(z - NE) * F_DIM);
  #pragma unroll
  for (int f = 0; f < 8; f++) {
    #pragma unroll
    for (int r = 0; r < 4; r++) {
      int row = wm * 128 + f * 16 + (lane >> 4) * 4 + r;
      float g = pair_gate[row0 + row];
      #pragma unroll
      for (int c = 0; c < 4; c++) {
        int col = bn * 256 + wn * 64 + c * 16 + (lane & 15);
        float v = acc[f][c][r] + b1[col];
        float h = 0.5f * v * (1.0f + erff(v * 0.70710678118654752440f));
        H[(size_t)(row0 + row) * F_DIM + col] = f2bf(h * g);
      }
    }
  }
}

// ---------------- GEMM2 unified: routed->Yr (K=512), shared->out (K=1024) ---
// grid (8, 104): x=bn (256-col tile of D=2048), y=slot. block 512.
__global__ __launch_bounds__(512, 2) void k_gemm2(
    const short* __restrict__ Hb, const short* __restrict__ w2t,
    const int* __restrict__ meta, const int* __restrict__ tile_z,
    const int* __restrict__ tile_row,
    const int2* __restrict__ ti, const float2* __restrict__ tg,
    const float* __restrict__ eb2, const float* __restrict__ sb2,
    short* __restrict__ Yr, float* __restrict__ out) {
  const int slot = blockIdx.y;
  const bool shmode = (slot >= MAX_RT256);
  if (!shmode && slot >= meta[18]) return;
  const int z = shmode ? 0 : tile_z[slot];
  const int row0 = shmode ? 0 : tile_row[slot];
  const int t0 = shmode ? (slot - MAX_RT256) * 256 : 0;
  const int bn = blockIdx.x;
  __shared__ __align__(16) short As[3][8192];
  __shared__ __align__(16) short Bs[3][8192];
  const int tid = threadIdx.x;
  const int lane = tid & 63;
  const int wv = tid >> 6;
  const int wm = wv >> 2;
  const int wn = wv & 3;
  const int ldo = (lane >> 4) * 128 + (lane & 15) * 8;

  const int srlow = (wv << 4) | (lane & 15);
  const int scol0 = (lane >> 4) * 8;

  f32x4 acc[8][4];
  #pragma unroll
  for (int m = 0; m < 8; m++)
    #pragma unroll
    for (int n = 0; n < 4; n++) acc[m][n] = (f32x4)(0.f);

  auto stA = [&](int buf, int h, int tt) {
    const short* p;
    if (shmode) {
      p = Hb + (size_t)(SH_B256 + ((tt >= 16) ? TOKENS : 0) + t0 + h * 128 + srlow) * F_DIM
            + (tt & 15) * 32 + scol0;
    } else {
      p = Hb + (size_t)(row0 + h * 128 + srlow) * F_DIM + tt * 32 + scol0;
    }
    gload_lds16(p, &As[buf][(h * 8 + wv) * 512]);
  };
  auto stB = [&](int buf, int h, int tt) {
    const short* p;
    if (shmode) {
      p = w2t + (size_t)(NE + ((tt >= 16) ? 1 : 0)) * D_DIM * F_DIM
              + (size_t)(bn * 256 + h * 128 + srlow) * F_DIM + (tt & 15) * 32 + scol0;
    } else {
      p = w2t + (size_t)z * D_DIM * F_DIM
              + (size_t)(bn * 256 + h * 128 + srlow) * F_DIM + tt * 32 + scol0;
    }
    gload_lds16(p, &Bs[buf][(h * 8 + wv) * 512]);
  };

  // prologue: tiles 0 -> buf0, 1 -> buf1
  stA(0, 0, 0); stA(0, 1, 0); stB(0, 0, 0); stB(0, 1, 0);
  stA(1, 0, 1); stA(1, 1, 1); stB(1, 0, 1); stB(1, 1, 1);

  const int NT = shmode ? 32 : 16;
  int rd = 0;
  for (int t = 0; t < NT; ++t) {
    const short* Acur = &As[rd][0];
    const short* Bcur = &Bs[rd][0];
    const int st = (rd + 2 >= 3) ? rd - 1 : rd + 2;
    const int tt = t + 2;
    KTILE_TOP(NT);
    bf16x8 afr[4], bfr[2];
    PH_CORE(0, 0, 1, 1, if (tt < NT) stA(st, 0, tt));
    PH_CORE(0, 1, 0, 1, if (tt < NT) stA(st, 1, tt));
    PH_CORE(1, 1, 1, 0, if (tt < NT) stB(st, 0, tt));
    PH_CORE(1, 0, 0, 1, if (tt < NT) stB(st, 1, tt));
    rd = (rd + 1 == 3) ? 0 : rd + 1;
  }

  if (!shmode) {
    #pragma unroll
    for (int f = 0; f < 8; f++) {
      #pragma unroll
      for (int r = 0; r < 4; r++) {
        int row = wm * 128 + f * 16 + (lane >> 4) * 4 + r;
        #pragma unroll
        for (int c = 0; c < 4; c++) {
          int col = bn * 256 + wn * 64 + c * 16 + (lane & 15);
          Yr[(size_t)(row0 + row) * D_DIM + col] = f2bf(acc[f][c][r]);
        }
      }
    }
  } else {
    #pragma unroll
    for (int f = 0; f < 8; f++) {
      #pragma unroll
      for (int r = 0; r < 4; r++) {
        int row = t0 + wm * 128 + f * 16 + (lane >> 4) * 4 + r;
        int2 ii = ti[row]; float2 gg = tg[row];
        #pragma unroll
        for (int c = 0; c < 4; c++) {
          int col = bn * 256 + wn * 64 + c * 16 + (lane & 15);
          float v = acc[f][c][r]
                  + gg.x * eb2[(size_t)ii.x * D_DIM + col]
                  + gg.y * eb2[(size_t)ii.y * D_DIM + col]
                  + sb2[col] + sb2[D_DIM + col];
          out[(size_t)row * D_DIM + col] = v;
        }
      }
    }
  }
}

// ---------------- combine: out[t] += Yr[pos0] + Yr[pos1] --------------------
__global__ __launch_bounds__(256) void k_combine(
    const short* __restrict__ Yr, const int2* __restrict__ pos,
    float* __restrict__ out) {
  int idx = blockIdx.x * 256 + threadIdx.x;   // over TOKENS*D_DIM/8
  int t = idx >> 8;
  int c = (idx & 255) * 8;
  int2 p = pos[t];
  bf16x8 a = *(const bf16x8*)&Yr[(size_t)p.x * D_DIM + c];
  bf16x8 b = *(const bf16x8*)&Yr[(size_t)p.y * D_DIM + c];
  float4 o0 = *(float4*)&out[(size_t)t * D_DIM + c];
  float4 o1 = *(float4*)&out[(size_t)t * D_DIM + c + 4];
  o0.x += bf2f(a[0]) + bf2f(b[0]);
  o0.y += bf2f(a[1]) + bf2f(b[1]);
  o0.z += bf2f(a[2]) + bf2f(b[2]);
  o0.w += bf2f(a[3]) + bf2f(b[3]);
  o1.x += bf2f(a[4]) + bf2f(b[4]);
  o1.y += bf2f(a[5]) + bf2f(b[5]);
  o1.z += bf2f(a[6]) + bf2f(b[6]);
  o1.w += bf2f(a[7]) + bf2f(b[7]);
  *(float4*)&out[(size_t)t * D_DIM + c] = o0;
  *(float4*)&out[(size_t)t * D_DIM + c + 4] = o1;
}

// ---------------------------------------------------------------------------
extern "C" void kernel_launch(void* const* d_in, const int* in_sizes, int n_in,
                              void* d_out, int out_size, void* d_ws, size_t ws_size,
                              hipStream_t stream) {
  (void)in_sizes; (void)n_in; (void)out_size; (void)ws_size;
  const float* x        = (const float*)d_in[0];
  const float* router_w = (const float*)d_in[1];
  const float* router_b = (const float*)d_in[2];
  const float* ew1      = (const float*)d_in[3];
  const float* eb1      = (const float*)d_in[4];
  const float* ew2      = (const float*)d_in[5];
  const float* eb2      = (const float*)d_in[6];
  const float* sw1      = (const float*)d_in[7];
  const float* sb1      = (const float*)d_in[8];
  const float* sw2      = (const float*)d_in[9];
  const float* sb2      = (const float*)d_in[10];
  float* out = (float*)d_out;

  // workspace layout (Yr aliases xb+w1t+overhang; dead after k_gemm1):
  //   w2t 20.97MB | Hbuf 35.65MB | small ~0.6MB | xb 33.55MB | w1t 20.97MB |
  //   Yr-overhang ~21MB  => total ~133MB
  char* ws = (char*)d_ws;
  short*  w2t       = (short*)ws;
  short*  Hbuf      = w2t + (size_t)NZ * D_DIM * F_DIM;
  int2*   ti        = (int2*)(Hbuf + (size_t)NPAIRS256 * F_DIM);
  float2* tg        = (float2*)(ti + TOKENS);
  int2*   pos       = (int2*)(tg + TOKENS);
  int*    pair_tok  = (int*)(pos + TOKENS);
  float*  pair_gate = (float*)(pair_tok + NPAIRS256);
  int*    meta      = (int*)(pair_gate + NPAIRS256);
  int*    tile_z    = meta + 32;
  int*    tile_row  = tile_z + 256;
  short*  xb        = (short*)(((uintptr_t)(tile_row + 256) + 255) & ~(uintptr_t)255);
  short*  w1t       = xb + (size_t)TOKENS * D_DIM;
  short*  Yr        = xb;   // alias (valid after k_gemm1 completes)

  k_transpose<<<dim3(F_DIM / 32, D_DIM / 32, NE),  dim3(32, 8), 0, stream>>>(ew1, w1t, D_DIM, F_DIM);
  k_transpose<<<dim3(F_DIM / 32, D_DIM / 32, NSH), dim3(32, 8), 0, stream>>>(sw1, w1t + (size_t)NE * F_DIM * D_DIM, D_DIM, F_DIM);
  k_transpose<<<dim3(D_DIM / 32, F_DIM / 32, NE),  dim3(32, 8), 0, stream>>>(ew2, w2t, F_DIM, D_DIM);
  k_transpose<<<dim3(D_DIM / 32, F_DIM / 32, NSH), dim3(32, 8), 0, stream>>>(sw2, w2t + (size_t)NE * D_DIM * F_DIM, F_DIM, D_DIM);

  k_init<<<(RCAP256 + 255) / 256, 256, 0, stream>>>(pair_tok, pair_gate);
  k_router<<<TOKENS / 4, 256, 0, stream>>>(x, router_w, router_b, xb, ti, tg);
  k_count<<<1, 1024, 0, stream>>>(ti, meta, tile_z, tile_row);
  k_assign<<<TOKENS / 256, 256, 0, stream>>>(ti, tg, meta, pair_tok, pair_gate, pos);
  k_loss<<<1, 64, 0, stream>>>(meta, out + OUT_ELEMS);

  k_gemm1<<<dim3(2, G1_SLOTS), 512, 0, stream>>>(
      xb, w1t, eb1, sb1, meta, tile_z, tile_row, pair_tok, pair_gate, Hbuf);
  k_gemm2<<<dim3(8, G2_SLOTS), 512, 0, stream>>>(
      Hbuf, w2t, meta, tile_z, tile_row, ti, tg, eb2, sb2, Yr, out);
  k_combine<<<OUT_ELEMS / 8 / 256, 256, 0, stream>>>(Yr, pos, out);
}